// Round 26
// baseline (160.574 us; speedup 1.0000x reference)
//
#include <hip/hip_runtime.h>

#define DIM     256
#define HW      1024
#define N_ROWS  65536
#define MARGIN  0.125f
#define MARGIN3 0.1875f

#define OUT_Q_OFF    16777216
#define OUT_LOSS_OFF 16842752

// ws: floats [0,512) c2 ; [512,2560) dist partials(2048) ; [2560,4608) x2 partials(2048)
// ints: [4608] full cnt ; [4609] pair cnt ; [5120,21504) full list ; [21504,119808) pair list (x3)
// bytes: [786432,1048576) lut fp16 fragment-linear (256KB)
#define WS_DIST    512
#define WS_X2      2560
#define WS_CNTF_I  4608
#define WS_CNTP_I  4609
#define WS_LISTF_I 5120
#define WS_LISTP_I 21504
#define CAP_F      16384
#define CAP_P      32768
#define WS_LUTH_B  786432

#define VQ_LDS 132096   // 128KB A-stage/B-half (recycled) + 1KB qsh

typedef _Float16 half8v __attribute__((ext_vector_type(8)));
typedef float floatx4 __attribute__((ext_vector_type(4)));

#define GLOAD_LDS16(gaddr, laddr) \
    __builtin_amdgcn_global_load_lds((const __attribute__((address_space(1))) unsigned int*)(gaddr), \
                                     (__attribute__((address_space(3))) unsigned int*)(laddr), 16, 0, 0)

__global__ void c2_kernel(const float* __restrict__ lut, float* __restrict__ ws) {
    if (threadIdx.x == 0) { ((int*)ws)[WS_CNTF_I] = 0; ((int*)ws)[WS_CNTP_I] = 0; }
    int t = threadIdx.x;
    for (int k = t; k < 512; k += 256) {
        const float4* row = (const float4*)(lut + (size_t)k * DIM);
        float s = 0.f;
        #pragma unroll 8
        for (int i = 0; i < DIM / 4; ++i) {
            float4 v = row[i];
            s += v.x * v.x + v.y * v.y + v.z * v.z + v.w * v.w;
        }
        ws[k] = s;
    }
}

// lut -> fp16 fragment-linear: chunk(dc*32+ctu)*1KB + lane*16B (R14-proven layout)
__global__ void lutprep_kernel(const float* __restrict__ lut, float* __restrict__ ws) {
    int g = blockIdx.x * 256 + threadIdx.x;    // 0..16383
    int lane = g & 63;
    int ctu  = (g >> 6) & 31;
    int dcg  = g >> 11;
    int code = ctu * 16 + (lane & 15);
    int d0   = dcg * 32 + (lane >> 4) * 8;
    const float* src = lut + (size_t)code * DIM + d0;
    half8v h;
    #pragma unroll
    for (int j = 0; j < 8; ++j) h[j] = (_Float16)src[j];
    char* dst = (char*)ws + WS_LUTH_B + (size_t)(dcg * 32 + ctu) * 1024 + lane * 16;
    *(half8v*)dst = h;
}

// merge triple (v1,i1,v2,i2,v3) <- union with (w1,j1,w2,j2,w3)  [R15-proven]
#define MERGE_TRIPLE(v1,i1,v2,i2,v3, w1,j1,w2,j2,w3)                          \
    {                                                                         \
        float a1,a2,a3,b1v,b2v; int a1i,a2i,b1i,b2i;                          \
        bool bf = (w1 < v1) || (w1 == v1 && j1 < i1);                         \
        if (bf) { a1=w1;a1i=j1;a2=w2;a2i=j2;a3=w3; b1v=v1;b1i=i1;b2v=v2;b2i=i2; } \
        else    { a1=v1;a1i=i1;a2=v2;a2i=i2;a3=v3; b1v=w1;b1i=j1;b2v=w2;b2i=j2; } \
        bool sa = (a2 < b1v) || (a2 == b1v && a2i < b1i);                     \
        v1 = a1; i1 = a1i;                                                    \
        if (sa) { v2 = a2; i2 = a2i; v3 = fminf(a3, b1v); }                   \
        else    { v2 = b1v; i2 = b1i; v3 = fminf(a2, b2v); }                  \
    }

__global__ __launch_bounds__(512, 1) void vq_kernel(const float* __restrict__ x,
                                                    const float* __restrict__ lut,
                                                    float* __restrict__ out,
                                                    float* __restrict__ ws) {
    extern __shared__ char smem[];   // [0,131072): A-stage then B halves ; [131072,132096): qsh
    int* qsh = (int*)(smem + 131072);      // [256]
    const char* luth = (const char*)ws + WS_LUTH_B;

    const int tid  = threadIdx.x;
    const int blk  = blockIdx.x;
    const int wave = tid >> 6;
    const int lane = tid & 63;
    const int l15  = lane & 15;
    const int l4   = lane >> 4;

    const int n0b = blk * 256;               // block's 256 consecutive rows
    const int b   = n0b >> 10;
    const int hw0 = n0b & 1023;
    const int n0w = n0b + wave * 32;         // this wave's 32 rows
    const float* xb = x + (size_t)b * (DIM * HW) + hw0;

    // ---- phase 1: block-cooperative A stage, 1KB-coalesced x reads ----
    // gid -> (d = gid>>6, r4 = gid&63): rows 4r4..4r4+3 of column d
    // LDS dest = per-wave fragment layout: chunk((row>>5)*16 + ((row>>4)&1)*8 + (d>>5)),
    //            byte (( (d>>3)&3 )*16 + (row&15))*16 + (d&7)*2   [bitwise = R25 frag contents]
    float x2local = 0.f;
    #pragma unroll 8
    for (int i = 0; i < 32; ++i) {
        int gid = i * 512 + tid;
        int d   = gid >> 6;
        int r4  = gid & 63;
        float4 v = *(const float4*)(xb + (size_t)d * HW + r4 * 4);
        x2local = fmaf(v.x, v.x, x2local);
        x2local = fmaf(v.y, v.y, x2local);
        x2local = fmaf(v.z, v.z, x2local);
        x2local = fmaf(v.w, v.w, x2local);
        const int chunk = (r4 >> 3) * 16 + ((r4 >> 2) & 1) * 8 + (d >> 5);
        const int lbase = ((d >> 3) & 3) * 16;
        const int joff  = (d & 7) * 2;
        char* cbp = smem + chunk * 1024;
        const float* vf = (const float*)&v;
        #pragma unroll
        for (int rr = 0; rr < 4; ++rr) {
            int row15 = 4 * (r4 & 3) + rr;
            *(_Float16*)(cbp + (lbase + row15) * 16 + joff) = (_Float16)vf[rr];
        }
    }
    __syncthreads();   // A staged

    // ---- phase 2: waves copy their A-frags to registers (conflict-free b128) ----
    half8v a[2][8];
    #pragma unroll
    for (int t = 0; t < 2; ++t)
        #pragma unroll
        for (int dc = 0; dc < 8; ++dc)
            a[t][dc] = *(const half8v*)(smem + (size_t)(wave * 16 + t * 8 + dc) * 1024 + lane * 16);

    // running top-3 per (t, r)
    float v1[2][4], v2[2][4], v3[2][4]; int i1[2][4], i2[2][4];
    #pragma unroll
    for (int t = 0; t < 2; ++t)
        #pragma unroll
        for (int r = 0; r < 4; ++r) { v1[t][r]=3.4e38f; v2[t][r]=3.4e38f; v3[t][r]=3.4e38f; i1[t][r]=0; i2[t][r]=0; }

    // ---- phase 3: two passes over code halves; B half resident in LDS (R25-proven) ----
    for (int p = 0; p < 2; ++p) {
        __syncthreads();   // p=0: all waves copied A; p=1: all waves done with half 0
        #pragma unroll
        for (int i = 0; i < 16; ++i) {
            int idx = i * 512 + tid;
            int ck  = idx >> 6;                       // LDS chunk 0..127
            int sc  = (ck >> 4) * 32 + p * 16 + (ck & 15);  // lutbf chunk
            GLOAD_LDS16(luth + (size_t)sc * 1024 + lane * 16, smem + ck * 1024);
        }
        __syncthreads();   // full drain: B half resident

        for (int cl = 0; cl < 16; ++cl) {
            half8v bh[8];
            #pragma unroll
            for (int dc = 0; dc < 8; ++dc)
                bh[dc] = *(const half8v*)(smem + (size_t)(dc * 16 + cl) * 1024 + lane * 16);
            floatx4 acc0 = (floatx4)0.f, acc1 = (floatx4)0.f;
            #pragma unroll
            for (int dc = 0; dc < 8; ++dc) {
                acc0 = __builtin_amdgcn_mfma_f32_16x16x32_f16(a[0][dc], bh[dc], acc0, 0, 0, 0);
                acc1 = __builtin_amdgcn_mfma_f32_16x16x32_f16(a[1][dc], bh[dc], acc1, 0, 0, 0);
            }
            const int code = (p * 16 + cl) * 16 + l15;
            const float c2v = ws[code];
            #pragma unroll
            for (int r = 0; r < 4; ++r) {
                float d0f = fmaf(-2.f, acc0[r], c2v);
                if (d0f < v1[0][r])      { v3[0][r]=v2[0][r]; v2[0][r]=v1[0][r]; i2[0][r]=i1[0][r]; v1[0][r]=d0f; i1[0][r]=code; }
                else if (d0f < v2[0][r]) { v3[0][r]=v2[0][r]; v2[0][r]=d0f; i2[0][r]=code; }
                else if (d0f < v3[0][r]) { v3[0][r]=d0f; }
                float d1f = fmaf(-2.f, acc1[r], c2v);
                if (d1f < v1[1][r])      { v3[1][r]=v2[1][r]; v2[1][r]=v1[1][r]; i2[1][r]=i1[1][r]; v1[1][r]=d1f; i1[1][r]=code; }
                else if (d1f < v2[1][r]) { v3[1][r]=v2[1][r]; v2[1][r]=d1f; i2[1][r]=code; }
                else if (d1f < v3[1][r]) { v3[1][r]=d1f; }
            }
        }
    }

    // ---- cross-lane top-3 merge over l15 group ----
    #pragma unroll
    for (int t = 0; t < 2; ++t) {
        #pragma unroll
        for (int r = 0; r < 4; ++r) {
            #pragma unroll
            for (int off = 1; off < 16; off <<= 1) {
                float w1 = __shfl_xor(v1[t][r], off, 64);
                int   j1 = __shfl_xor(i1[t][r], off, 64);
                float w2 = __shfl_xor(v2[t][r], off, 64);
                int   j2 = __shfl_xor(i2[t][r], off, 64);
                float w3 = __shfl_xor(v3[t][r], off, 64);
                MERGE_TRIPLE(v1[t][r], i1[t][r], v2[t][r], i2[t][r], v3[t][r], w1, j1, w2, j2, w3);
            }
        }
    }

    // ---- q write, flags, dist partial (holder lanes l15==0; rows t*16 + l4*4 + r) ----
    float dist_part = 0.f;
    if (l15 == 0) {
        #pragma unroll
        for (int t = 0; t < 2; ++t) {
            #pragma unroll
            for (int r = 0; r < 4; ++r) {
                int row = t * 16 + l4 * 4 + r;
                int n1 = i1[t][r];
                qsh[wave * 32 + row] = n1;
                out[OUT_Q_OFF + n0w + row] = (float)n1;
                float m1 = v1[t][r], m2 = v2[t][r], m3 = v3[t][r];
                if (m2 - m1 <= MARGIN) {
                    if (m3 - m1 > MARGIN3) {
                        int idx = atomicAdd((int*)ws + WS_CNTP_I, 1);
                        if (idx < CAP_P) {
                            ((int*)ws)[WS_LISTP_I + idx * 3 + 0] = n0w + row;
                            ((int*)ws)[WS_LISTP_I + idx * 3 + 1] = n1;
                            ((int*)ws)[WS_LISTP_I + idx * 3 + 2] = i2[t][r];
                        }
                    } else {
                        int idx = atomicAdd((int*)ws + WS_CNTF_I, 1);
                        if (idx < CAP_F) ((int*)ws)[WS_LISTF_I + idx] = n0w + row;
                    }
                }
                dist_part += m1;
            }
        }
    }
    float dv = dist_part;
    #pragma unroll
    for (int off = 32; off; off >>= 1) dv += __shfl_down(dv, off, 64);
    if (lane == 0) ws[WS_DIST + blk * 8 + wave] = dv;
    float xv = x2local;
    #pragma unroll
    for (int off = 32; off; off >>= 1) xv += __shfl_down(xv, off, 64);
    if (lane == 0) ws[WS_X2 + blk * 8 + wave] = xv;

    __syncthreads();   // qsh published

    // ---- phase 5: x_e write, 1KB-coalesced stores; lut gathers from L2 ----
    #pragma unroll 8
    for (int i = 0; i < 32; ++i) {
        int gid = i * 512 + tid;
        int d   = gid >> 6;
        int r4  = gid & 63;
        float4 c;
        float* cp = (float*)&c;
        #pragma unroll
        for (int rr = 0; rr < 4; ++rr)
            cp[rr] = lut[(size_t)qsh[4 * r4 + rr] * DIM + d];
        *(float4*)(out + (size_t)b * (DIM * HW) + (size_t)d * HW + hw0 + r4 * 4) = c;
    }
}

// recheck: ONE BLOCK PER FLAGGED ROW (R21-proven; cooperative staging)
__global__ void recheck_kernel(const float* __restrict__ x, const float* __restrict__ lut,
                               float* __restrict__ out, const float* __restrict__ ws) {
    __shared__ float xrow[DIM];
    __shared__ float carow[DIM];
    __shared__ float cbrow[DIM];
    __shared__ float frv[256];
    __shared__ int   fri[256];
    __shared__ int   qq;
    const int tid = threadIdx.x;

    int cntp = ((const int*)ws)[WS_CNTP_I];
    if (cntp > CAP_P) cntp = CAP_P;
    const int* lp = (const int*)ws + WS_LISTP_I;
    for (int e = blockIdx.x; e < cntp; e += gridDim.x) {
        const int row = lp[e * 3 + 0];
        const int ia  = lp[e * 3 + 1];
        const int ib  = lp[e * 3 + 2];
        const int b = row >> 10, hw = row & 1023;
        xrow[tid]  = x[(size_t)b * (DIM * HW) + (size_t)tid * HW + hw];
        carow[tid] = lut[(size_t)ia * DIM + tid];
        cbrow[tid] = lut[(size_t)ib * DIM + tid];
        __syncthreads();
        if (tid == 0) {
            float dota = 0.f, dotb = 0.f;
            for (int d = 0; d < DIM; ++d) {
                dota = fmaf(xrow[d], carow[d], dota);
                dotb = fmaf(xrow[d], cbrow[d], dotb);
            }
            float da = fmaf(-2.f, dota, ws[ia]);
            float db = fmaf(-2.f, dotb, ws[ib]);
            int q;
            if (da < db) q = ia;
            else if (db < da) q = ib;
            else q = (ia < ib) ? ia : ib;
            qq = q;
            out[OUT_Q_OFF + row] = (float)q;
        }
        __syncthreads();
        const int q = qq;
        out[(size_t)b * (DIM * HW) + (size_t)tid * HW + hw] = lut[(size_t)q * DIM + tid];
        __syncthreads();
    }

    int cntf = ((const int*)ws)[WS_CNTF_I];
    if (cntf > CAP_F) cntf = CAP_F;
    const int* lf = (const int*)ws + WS_LISTF_I;
    for (int e = blockIdx.x; e < cntf; e += gridDim.x) {
        const int row = lf[e];
        const int b = row >> 10, hw = row & 1023;
        xrow[tid] = x[(size_t)b * (DIM * HW) + (size_t)tid * HW + hw];
        __syncthreads();
        float bv = 3.4e38f; int bi = 0;
        #pragma unroll
        for (int k2 = 0; k2 < 2; ++k2) {
            int k = tid + k2 * 256;
            const float* cr = lut + (size_t)k * DIM;
            float dot = 0.f;
            for (int d = 0; d < DIM; ++d) dot = fmaf(xrow[d], cr[d], dot);
            float dist = fmaf(-2.f, dot, ws[k]);
            if (dist < bv || (dist == bv && k < bi)) { bv = dist; bi = k; }
        }
        frv[tid] = bv; fri[tid] = bi;
        __syncthreads();
        for (int s = 128; s; s >>= 1) {
            if (tid < s) {
                float ov = frv[tid + s]; int oi = fri[tid + s];
                if (ov < frv[tid] || (ov == frv[tid] && oi < fri[tid])) {
                    frv[tid] = ov; fri[tid] = oi;
                }
            }
            __syncthreads();
        }
        const int q = fri[0];
        if (tid == 0) out[OUT_Q_OFF + row] = (float)q;
        out[(size_t)b * (DIM * HW) + (size_t)tid * HW + hw] = lut[(size_t)q * DIM + tid];
        __syncthreads();
    }
}

__global__ void loss_kernel(float* __restrict__ out, const float* __restrict__ ws) {
    __shared__ float wsum[4];
    int tid = threadIdx.x;
    float s = 0.f;
    for (int i = tid; i < 4096; i += 256) s += ws[WS_DIST + i];   // dist[512,2560) + x2[2560,4608)
    #pragma unroll
    for (int off = 32; off; off >>= 1) s += __shfl_down(s, off, 64);
    if ((tid & 63) == 0) wsum[tid >> 6] = s;
    __syncthreads();
    if (tid == 0) {
        float total = wsum[0] + wsum[1] + wsum[2] + wsum[3];
        out[OUT_LOSS_OFF] = total * (1.25f / 16777216.f);
    }
}

extern "C" void kernel_launch(void* const* d_in, const int* in_sizes, int n_in,
                              void* d_out, int out_size, void* d_ws, size_t ws_size,
                              hipStream_t stream) {
    const float* x   = (const float*)d_in[0];
    const float* lut = (const float*)d_in[1];
    float* out = (float*)d_out;
    float* ws  = (float*)d_ws;

    (void)hipFuncSetAttribute((const void*)vq_kernel,
                              hipFuncAttributeMaxDynamicSharedMemorySize, VQ_LDS);

    c2_kernel<<<1, 256, 0, stream>>>(lut, ws);
    lutprep_kernel<<<64, 256, 0, stream>>>(lut, ws);
    vq_kernel<<<256, 512, VQ_LDS, stream>>>(x, lut, out, ws);
    recheck_kernel<<<2048, 256, 0, stream>>>(x, lut, out, ws);
    loss_kernel<<<1, 256, 0, stream>>>(out, ws);
}

// Round 27
// 121.010 us; speedup vs baseline: 1.3269x; 1.3269x over previous
//
#include <hip/hip_runtime.h>

#define DIM     256
#define HW      1024
#define N_ROWS  65536
#define NT      256
#define QBM     32
#define NBLK    2048
#define MARGIN  0.125f
#define MARGIN3 0.1875f

#define OUT_Q_OFF    16777216
#define OUT_LOSS_OFF 16842752

// ws: floats [0,512) c2 ; [512,2560) dist partials(2048) ; [2560,4608) x2 partials(2048)
// ints: [4608] full cnt ; [4609] pair cnt ; [5120,21504) full list ; [21504,119808) pair list (x3)
// bytes: [786432,1048576) lut fp16 fragment-linear (256KB)
#define WS_DIST    512
#define WS_X2      2560
#define WS_CNTF_I  4608
#define WS_CNTP_I  4609
#define WS_LISTF_I 5120
#define WS_LISTP_I 21504
#define CAP_F      16384
#define CAP_P      32768
#define WS_LUTH_B  786432

#define VQ_LDS 49152   // 32KB B + 16KB A

typedef _Float16 half8v __attribute__((ext_vector_type(8)));
typedef float floatx4 __attribute__((ext_vector_type(4)));

#define GLOAD_LDS16(gaddr, laddr) \
    __builtin_amdgcn_global_load_lds((const __attribute__((address_space(1))) unsigned int*)(gaddr), \
                                     (__attribute__((address_space(3))) unsigned int*)(laddr), 16, 0, 0)

// fused prep: all blocks do lutprep; block 0 also computes c2 + inits counters
__global__ void prep_kernel(const float* __restrict__ lut, float* __restrict__ ws) {
    int g = blockIdx.x * 256 + threadIdx.x;    // 0..16383
    int lane = g & 63;
    int ctu  = (g >> 6) & 31;
    int dcg  = g >> 11;
    int code = ctu * 16 + (lane & 15);
    int d0   = dcg * 32 + (lane >> 4) * 8;
    const float* src = lut + (size_t)code * DIM + d0;
    half8v h;
    #pragma unroll
    for (int j = 0; j < 8; ++j) h[j] = (_Float16)src[j];
    char* dst = (char*)ws + WS_LUTH_B + (size_t)(dcg * 32 + ctu) * 1024 + lane * 16;
    *(half8v*)dst = h;

    if (blockIdx.x == 0) {
        if (threadIdx.x == 0) { ((int*)ws)[WS_CNTF_I] = 0; ((int*)ws)[WS_CNTP_I] = 0; }
        for (int k = threadIdx.x; k < 512; k += 256) {
            const float4* row = (const float4*)(lut + (size_t)k * DIM);
            float s = 0.f;
            #pragma unroll 8
            for (int i = 0; i < DIM / 4; ++i) {
                float4 v = row[i];
                s += v.x * v.x + v.y * v.y + v.z * v.z + v.w * v.w;
            }
            ws[k] = s;
        }
    }
}

// merge triple (v1,i1,v2,i2,v3) <- union with (w1,j1,w2,j2,w3)  [R15-proven]
#define MERGE_TRIPLE(v1,i1,v2,i2,v3, w1,j1,w2,j2,w3)                          \
    {                                                                         \
        float a1,a2,a3,b1v,b2v; int a1i,a2i,b1i,b2i;                          \
        bool bf = (w1 < v1) || (w1 == v1 && j1 < i1);                         \
        if (bf) { a1=w1;a1i=j1;a2=w2;a2i=j2;a3=w3; b1v=v1;b1i=i1;b2v=v2;b2i=i2; } \
        else    { a1=v1;a1i=i1;a2=v2;a2i=i2;a3=v3; b1v=w1;b1i=j1;b2v=w2;b2i=j2; } \
        bool sa = (a2 < b1v) || (a2 == b1v && a2i < b1i);                     \
        v1 = a1; i1 = a1i;                                                    \
        if (sa) { v2 = a2; i2 = a2i; v3 = fminf(a3, b1v); }                   \
        else    { v2 = b1v; i2 = b1i; v3 = fminf(a2, b2v); }                  \
    }

__global__ __launch_bounds__(NT, 3) void vq_kernel(const float* __restrict__ x,
                                                   const float* __restrict__ lut,
                                                   float* __restrict__ out,
                                                   float* __restrict__ ws) {
    extern __shared__ char smem[];
    // [0,32768): B buffer (R14 layout; chunks wave*8..+7 wave-private) ; [32768,49152): A
    char* asmem = smem + 32768;
    const char* luth = (const char*)ws + WS_LUTH_B;

    const int tid = threadIdx.x;
    const int blk = blockIdx.x;
    const int n0  = blk * QBM;
    const int b   = n0 >> 10;
    const int hw0 = n0 & 1023;
    const float* xb = x + (size_t)b * (DIM * HW) + hw0;

    const int wave = tid >> 6;
    const int lane = tid & 63;
    const int l15  = lane & 15;
    const int l4   = lane >> 4;
    const int cg   = wave;

    // ---- stage A once: float4 over hw (4 rows x 8 d per thread) ----
    float x2local = 0.f;
    {
        const int h = tid & 7;        // hw base = 4h
        const int g = tid >> 3;       // d = 8g..8g+7
        const int dc = g >> 2, o = g & 3;
        float4 v[8];
        #pragma unroll
        for (int j = 0; j < 8; ++j)
            v[j] = *(const float4*)(xb + (size_t)(8 * g + j) * HW + 4 * h);
        #pragma unroll
        for (int j = 0; j < 8; ++j) {
            x2local = fmaf(v[j].x, v[j].x, x2local);
            x2local = fmaf(v[j].y, v[j].y, x2local);
            x2local = fmaf(v[j].z, v[j].z, x2local);
            x2local = fmaf(v[j].w, v[j].w, x2local);
        }
        #pragma unroll
        for (int r = 0; r < 4; ++r) {
            int row = 4 * h + r;
            half8v hh;
            #pragma unroll
            for (int j = 0; j < 8; ++j) {
                const float* vf = (const float*)&v[j];
                hh[j] = (_Float16)vf[r];
            }
            char* dst = asmem + (size_t)((row >> 4) * 8 + dc) * 1024 + (((row & 15) + 16 * o) * 16);
            *(half8v*)dst = hh;
        }
    }

    floatx4 acc[2][8];
    #pragma unroll
    for (int i = 0; i < 2; ++i)
        #pragma unroll
        for (int j = 0; j < 8; ++j) acc[i][j] = (floatx4)0.f;

    // ---- prologue: issue wave-private B DMA for dc=0 ----
    #pragma unroll
    for (int i = 0; i < 8; ++i) {
        int cc = wave * 8 + i;
        GLOAD_LDS16(luth + (size_t)(0 * 32 + cc) * 1024 + lane * 16, smem + cc * 1024);
    }
    __syncthreads();   // publishes A (full drain also lands DMA0)

    // ---- barrier-free K loop: wave-private B, counted in-wave waits (R20-proven) ----
    for (int dc = 0; dc < 8; ++dc) {
        asm volatile("s_waitcnt vmcnt(0)" ::: "memory");   // my DMA for dc landed
        __builtin_amdgcn_sched_barrier(0);
        half8v ah[2], bh[8];
        #pragma unroll
        for (int rtl = 0; rtl < 2; ++rtl)
            ah[rtl] = *(const half8v*)(asmem + (size_t)(rtl * 8 + dc) * 1024 + lane * 16);
        #pragma unroll
        for (int ct = 0; ct < 8; ++ct)
            bh[ct] = *(const half8v*)(smem + (size_t)(cg * 8 + ct) * 1024 + lane * 16);
        asm volatile("s_waitcnt lgkmcnt(0)" ::: "memory"); // my reads are in regs
        __builtin_amdgcn_sched_barrier(0);
        if (dc < 7) {  // overwrite my chunks with dc+1; overlaps the MFMAs below
            #pragma unroll
            for (int i = 0; i < 8; ++i) {
                int cc = wave * 8 + i;
                GLOAD_LDS16(luth + (size_t)((dc + 1) * 32 + cc) * 1024 + lane * 16, smem + cc * 1024);
            }
        }
        #pragma unroll
        for (int ct = 0; ct < 8; ++ct)
            #pragma unroll
            for (int rtl = 0; rtl < 2; ++rtl)
                acc[rtl][ct] = __builtin_amdgcn_mfma_f32_16x16x32_f16(ah[rtl], bh[ct], acc[rtl][ct], 0, 0, 0);
    }
    __syncthreads();   // all waves done with B region; becomes overlays

    // overlays on dead B buffer
    float* rv1   = (float*)smem;              // [4][32]
    int*   ri1   = (int*)(smem + 512);
    float* rv2   = (float*)(smem + 1024);
    int*   ri2   = (int*)(smem + 1536);
    float* rv3   = (float*)(smem + 2048);
    int*   qsh   = (int*)(smem + 2560);       // [32]
    float* wsumx = (float*)(smem + 2688);     // [4]

    // ---- per-row top-3 within wave (codes cg*128..+127, ct ascending) ----
    #pragma unroll
    for (int rt = 0; rt < 2; ++rt) {
        #pragma unroll
        for (int r = 0; r < 4; ++r) {
            float v1 = 3.4e38f, v2 = 3.4e38f, v3 = 3.4e38f; int i1 = 0, i2 = 0;
            #pragma unroll
            for (int ct = 0; ct < 8; ++ct) {
                int code = (cg * 8 + ct) * 16 + l15;
                float dist = fmaf(-2.f, acc[rt][ct][r], ws[code]);
                if (dist < v1)      { v3 = v2; v2 = v1; i2 = i1; v1 = dist; i1 = code; }
                else if (dist < v2) { v3 = v2; v2 = dist; i2 = code; }
                else if (dist < v3) { v3 = dist; }
            }
            #pragma unroll
            for (int off = 1; off < 16; off <<= 1) {
                float w1 = __shfl_xor(v1, off, 64);
                int   j1 = __shfl_xor(i1, off, 64);
                float w2 = __shfl_xor(v2, off, 64);
                int   j2 = __shfl_xor(i2, off, 64);
                float w3 = __shfl_xor(v3, off, 64);
                MERGE_TRIPLE(v1, i1, v2, i2, v3, w1, j1, w2, j2, w3);
            }
            if (l15 == 0) {
                int idx = cg * 32 + rt * 16 + l4 * 4 + r;
                rv1[idx] = v1; ri1[idx] = i1; rv2[idx] = v2; ri2[idx] = i2; rv3[idx] = v3;
            }
        }
    }
    __syncthreads();

    float dist_part = 0.f;
    if (tid < QBM) {
        const int row = tid;
        float m1 = rv1[row]; int n1 = ri1[row]; float m2 = rv2[row]; int n2 = ri2[row]; float m3 = rv3[row];
        #pragma unroll
        for (int s = 1; s < 4; ++s) {
            float w1 = rv1[s * 32 + row]; int j1 = ri1[s * 32 + row];
            float w2 = rv2[s * 32 + row]; int j2 = ri2[s * 32 + row];
            float w3 = rv3[s * 32 + row];
            MERGE_TRIPLE(m1, n1, m2, n2, m3, w1, j1, w2, j2, w3);
        }
        qsh[row] = n1;
        out[OUT_Q_OFF + n0 + row] = (float)n1;
        if (m2 - m1 <= MARGIN) {
            if (m3 - m1 > MARGIN3) {
                int idx = atomicAdd((int*)ws + WS_CNTP_I, 1);
                if (idx < CAP_P) {
                    ((int*)ws)[WS_LISTP_I + idx * 3 + 0] = n0 + row;
                    ((int*)ws)[WS_LISTP_I + idx * 3 + 1] = n1;
                    ((int*)ws)[WS_LISTP_I + idx * 3 + 2] = n2;
                }
            } else {
                int idx = atomicAdd((int*)ws + WS_CNTF_I, 1);
                if (idx < CAP_F) ((int*)ws)[WS_LISTF_I + idx] = n0 + row;
            }
        }
        dist_part = m1;
    }
    float dv = dist_part;
    #pragma unroll
    for (int off = 32; off; off >>= 1) dv += __shfl_down(dv, off, 64);
    if (tid == 0) ws[WS_DIST + blk] = dv;

    float xv = x2local;
    #pragma unroll
    for (int off = 32; off; off >>= 1) xv += __shfl_down(xv, off, 64);
    if (lane == 0) wsumx[wave] = xv;
    __syncthreads();   // qsh + wsumx ready
    if (tid == 0) ws[WS_X2 + blk] = wsumx[0] + wsumx[1] + wsumx[2] + wsumx[3];

    // ---- x_e write: float4 over hw, lut gathers from L2 (recheck patches flagged rows) ----
    {
        const int h = tid & 7;        // hw base = 4h
        const int g = tid >> 3;       // d = 8g..8g+7
        int qs[4];
        #pragma unroll
        for (int r = 0; r < 4; ++r) qs[r] = qsh[4 * h + r];
        float* ob = out + (size_t)b * (DIM * HW) + hw0 + 4 * h;
        #pragma unroll
        for (int j = 0; j < 8; ++j) {
            int d = 8 * g + j;
            float4 c;
            float* cp = (float*)&c;
            #pragma unroll
            for (int r = 0; r < 4; ++r) cp[r] = lut[(size_t)qs[r] * DIM + d];
            *(float4*)(ob + (size_t)d * HW) = c;
        }
    }
}

// fused recheck + loss: blocks recheck flagged rows; block 0 additionally computes loss
__global__ void recheck_kernel(const float* __restrict__ x, const float* __restrict__ lut,
                               float* __restrict__ out, const float* __restrict__ ws) {
    __shared__ float xrow[DIM];
    __shared__ float carow[DIM];
    __shared__ float cbrow[DIM];
    __shared__ float frv[256];
    __shared__ int   fri[256];
    __shared__ int   qq;
    __shared__ float wsum[4];
    const int tid = threadIdx.x;

    // ---- loss (block 0; vq partials complete by stream order) ----
    if (blockIdx.x == 0) {
        float s = 0.f;
        for (int i = tid; i < 4096; i += 256) s += ws[WS_DIST + i];   // dist + x2 ranges
        #pragma unroll
        for (int off = 32; off; off >>= 1) s += __shfl_down(s, off, 64);
        if ((tid & 63) == 0) wsum[tid >> 6] = s;
        __syncthreads();
        if (tid == 0) {
            float total = wsum[0] + wsum[1] + wsum[2] + wsum[3];
            out[OUT_LOSS_OFF] = total * (1.25f / 16777216.f);
        }
        __syncthreads();
    }

    int cntp = ((const int*)ws)[WS_CNTP_I];
    if (cntp > CAP_P) cntp = CAP_P;
    const int* lp = (const int*)ws + WS_LISTP_I;
    for (int e = blockIdx.x; e < cntp; e += gridDim.x) {
        const int row = lp[e * 3 + 0];
        const int ia  = lp[e * 3 + 1];
        const int ib  = lp[e * 3 + 2];
        const int b = row >> 10, hw = row & 1023;
        xrow[tid]  = x[(size_t)b * (DIM * HW) + (size_t)tid * HW + hw];
        carow[tid] = lut[(size_t)ia * DIM + tid];
        cbrow[tid] = lut[(size_t)ib * DIM + tid];
        __syncthreads();
        if (tid == 0) {
            float dota = 0.f, dotb = 0.f;
            for (int d = 0; d < DIM; ++d) {
                dota = fmaf(xrow[d], carow[d], dota);
                dotb = fmaf(xrow[d], cbrow[d], dotb);
            }
            float da = fmaf(-2.f, dota, ws[ia]);
            float db = fmaf(-2.f, dotb, ws[ib]);
            int q;
            if (da < db) q = ia;
            else if (db < da) q = ib;
            else q = (ia < ib) ? ia : ib;
            qq = q;
            out[OUT_Q_OFF + row] = (float)q;
        }
        __syncthreads();
        const int q = qq;
        out[(size_t)b * (DIM * HW) + (size_t)tid * HW + hw] = lut[(size_t)q * DIM + tid];
        __syncthreads();
    }

    int cntf = ((const int*)ws)[WS_CNTF_I];
    if (cntf > CAP_F) cntf = CAP_F;
    const int* lf = (const int*)ws + WS_LISTF_I;
    for (int e = blockIdx.x; e < cntf; e += gridDim.x) {
        const int row = lf[e];
        const int b = row >> 10, hw = row & 1023;
        xrow[tid] = x[(size_t)b * (DIM * HW) + (size_t)tid * HW + hw];
        __syncthreads();
        float bv = 3.4e38f; int bi = 0;
        #pragma unroll
        for (int k2 = 0; k2 < 2; ++k2) {
            int k = tid + k2 * 256;
            const float* cr = lut + (size_t)k * DIM;
            float dot = 0.f;
            for (int d = 0; d < DIM; ++d) dot = fmaf(xrow[d], cr[d], dot);
            float dist = fmaf(-2.f, dot, ws[k]);
            if (dist < bv || (dist == bv && k < bi)) { bv = dist; bi = k; }
        }
        frv[tid] = bv; fri[tid] = bi;
        __syncthreads();
        for (int s = 128; s; s >>= 1) {
            if (tid < s) {
                float ov = frv[tid + s]; int oi = fri[tid + s];
                if (ov < frv[tid] || (ov == frv[tid] && oi < fri[tid])) {
                    frv[tid] = ov; fri[tid] = oi;
                }
            }
            __syncthreads();
        }
        const int q = fri[0];
        if (tid == 0) out[OUT_Q_OFF + row] = (float)q;
        out[(size_t)b * (DIM * HW) + (size_t)tid * HW + hw] = lut[(size_t)q * DIM + tid];
        __syncthreads();
    }
}

extern "C" void kernel_launch(void* const* d_in, const int* in_sizes, int n_in,
                              void* d_out, int out_size, void* d_ws, size_t ws_size,
                              hipStream_t stream) {
    const float* x   = (const float*)d_in[0];
    const float* lut = (const float*)d_in[1];
    float* out = (float*)d_out;
    float* ws  = (float*)d_ws;

    (void)hipFuncSetAttribute((const void*)vq_kernel,
                              hipFuncAttributeMaxDynamicSharedMemorySize, VQ_LDS);

    prep_kernel<<<64, 256, 0, stream>>>(lut, ws);
    vq_kernel<<<NBLK, NT, VQ_LDS, stream>>>(x, lut, out, ws);
    recheck_kernel<<<2048, 256, 0, stream>>>(x, lut, out, ws);
}